// Round 8
// baseline (240.508 us; speedup 1.0000x reference)
//
#include <hip/hip_runtime.h>
#include <hip/hip_bf16.h>
#include <cstdint>

// Problem constants (from reference): B=4, T=2048, D=512, FF=2048, E=8, K=2
#define NTOK   8192      // B*T
#define DDIM   512
#define FDIM   2048
#define NEXP   8
#define NSLOT  16384     // 2*NTOK assignments (top-2, always exactly 2 per token)
#define MAXT256 72       // sum_e ceil(cnt_e/256) <= 16384/256 + 8

typedef __bf16 bf16;
typedef __bf16 bf16x8 __attribute__((ext_vector_type(8)));
typedef float  f32x4  __attribute__((ext_vector_type(4)));

typedef uint32_t __attribute__((address_space(1))) gu32;
typedef uint32_t __attribute__((address_space(3))) lu32;

// async global->LDS, 16B per lane; LDS dest must be wave-uniform base (+lane*16 implicit)
__device__ __forceinline__ void gload16(const void* g, void* l) {
    __builtin_amdgcn_global_load_lds((const gu32*)(uintptr_t)g,
                                     (lu32*)(uintptr_t)l, 16, 0, 0);
}

// ---------------- gating: logits -> softmax -> top2 -> weights; also x->bf16 ----
__global__ __launch_bounds__(256)
void gating_kernel(const float* __restrict__ x, const float* __restrict__ Wg,
                   const float* __restrict__ bg, bf16* __restrict__ xb,
                   int* __restrict__ top_idx, float* __restrict__ top_w,
                   int* __restrict__ counts)
{
    __shared__ int cnt_s[NEXP];
    if (threadIdx.x < NEXP) cnt_s[threadIdx.x] = 0;
    __syncthreads();

    const int w = threadIdx.x >> 6;
    const int l = threadIdx.x & 63;
    const int gw = blockIdx.x * 4 + w;   // 1024 blocks * 4 waves = 4096 waves

    for (int n = gw; n < NTOK; n += 4096) {
        const float4* xp = (const float4*)(x + (size_t)n * DDIM + l * 8);
        float4 x0 = xp[0], x1 = xp[1];
        float xf[8] = {x0.x, x0.y, x0.z, x0.w, x1.x, x1.y, x1.z, x1.w};

        bf16x8 xv;
#pragma unroll
        for (int i = 0; i < 8; ++i) xv[i] = (bf16)xf[i];
        *(bf16x8*)(xb + (size_t)n * DDIM + l * 8) = xv;

        float acc[8] = {0.f,0.f,0.f,0.f,0.f,0.f,0.f,0.f};
#pragma unroll
        for (int i = 0; i < 8; ++i) {
            const float4* wp = (const float4*)(Wg + (size_t)(l * 8 + i) * NEXP);
            float4 wa = wp[0], wb = wp[1];
            acc[0] += xf[i] * wa.x; acc[1] += xf[i] * wa.y;
            acc[2] += xf[i] * wa.z; acc[3] += xf[i] * wa.w;
            acc[4] += xf[i] * wb.x; acc[5] += xf[i] * wb.y;
            acc[6] += xf[i] * wb.z; acc[7] += xf[i] * wb.w;
        }
#pragma unroll
        for (int m = 32; m >= 1; m >>= 1)
#pragma unroll
            for (int e = 0; e < 8; ++e)
                acc[e] += __shfl_xor(acc[e], m);

        if (l == 0) {
            float logit[8];
#pragma unroll
            for (int e = 0; e < 8; ++e) logit[e] = acc[e] + bg[e];
            float mx = logit[0];
#pragma unroll
            for (int e = 1; e < 8; ++e) mx = fmaxf(mx, logit[e]);
            float g[8], s = 0.f;
#pragma unroll
            for (int e = 0; e < 8; ++e) { g[e] = expf(logit[e] - mx); s += g[e]; }
            float inv = 1.f / s;
#pragma unroll
            for (int e = 0; e < 8; ++e) g[e] *= inv;
            // top-2, ties -> lower index first (matches lax.top_k)
            int e0 = 0;
#pragma unroll
            for (int e = 1; e < 8; ++e) if (g[e] > g[e0]) e0 = e;
            int e1 = (e0 == 0) ? 1 : 0;
#pragma unroll
            for (int e = 0; e < 8; ++e) if (e != e0 && e != e1 && g[e] > g[e1]) e1 = e;
            float denom = g[e0] + g[e1] + 0.01f;
            top_idx[n * 2 + 0] = e0;
            top_idx[n * 2 + 1] = e1;
            top_w[n * 2 + 0] = g[e0] / denom;
            top_w[n * 2 + 1] = g[e1] / denom;
            atomicAdd(&cnt_s[e0], 1);
            atomicAdd(&cnt_s[e1], 1);
        }
    }
    __syncthreads();
    if (threadIdx.x < NEXP) atomicAdd(&counts[threadIdx.x], cnt_s[threadIdx.x]);
}

// ---------------- scan: offsets, 256-granule tile map, zero cursors -------------
__global__ void scan_kernel(const int* __restrict__ counts, int* __restrict__ offsets,
                            int* __restrict__ tmap_e, int* __restrict__ tmap_rt,
                            int* __restrict__ ntiles, int* __restrict__ cursors)
{
    if (threadIdx.x == 0) {
        int off = 0;
        for (int e = 0; e < NEXP; ++e) { offsets[e] = off; off += counts[e]; cursors[e] = 0; }
        offsets[NEXP] = off;
        int t = 0;
        for (int e = 0; e < NEXP; ++e) {
            int nt = (counts[e] + 255) >> 8;
            for (int rt = 0; rt < nt; ++rt) { tmap_e[t] = e; tmap_rt[t] = rt; ++t; }
        }
        *ntiles = t;
    }
}

// ---------------- scatter: block-aggregated cursor reservation ------------------
__global__ __launch_bounds__(256)
void scatter_kernel(const int* __restrict__ top_idx, const float* __restrict__ top_w,
                    const int* __restrict__ offsets, int* __restrict__ cursors,
                    int* __restrict__ slot_tok, float* __restrict__ slot_w,
                    int* __restrict__ pos)
{
    __shared__ int lcnt[NEXP];
    __shared__ int lbase[NEXP];
    const int t = threadIdx.x;
    if (t < NEXP) lcnt[t] = 0;
    __syncthreads();
    const int n = blockIdx.x * 256 + t;   // NTOK = 32*256 exactly
    const int e0 = top_idx[n * 2 + 0];
    const int e1 = top_idx[n * 2 + 1];
    const int r0 = atomicAdd(&lcnt[e0], 1);
    const int r1 = atomicAdd(&lcnt[e1], 1);
    __syncthreads();
    if (t < NEXP) lbase[t] = atomicAdd(&cursors[t], lcnt[t]);
    __syncthreads();
    const int s0 = offsets[e0] + lbase[e0] + r0;
    const int s1 = offsets[e1] + lbase[e1] + r1;
    slot_tok[s0] = n; slot_w[s0] = top_w[n * 2 + 0]; pos[n * 2 + 0] = s0;
    slot_tok[s1] = n; slot_w[s1] = top_w[n * 2 + 1]; pos[n * 2 + 1] = s1;
}

// ---------------- fp32 [E][R][C] -> bf16 [E][C][R] transpose+convert ------------
__global__ __launch_bounds__(256)
void transpose_cvt(const float* __restrict__ src, bf16* __restrict__ dst, int R, int C)
{
    __shared__ bf16 tile[64][72];   // 72 = 16B-aligned row stride, rotates banks
    const size_t eo = (size_t)blockIdx.z * R * C;
    src += eo; dst += eo;
    const int c0 = blockIdx.x * 64, r0 = blockIdx.y * 64;
    const int tq = (threadIdx.x & 15) * 4;   // col quad within 64
    const int tr = threadIdx.x >> 4;         // 16 rows per pass
#pragma unroll
    for (int j = 0; j < 4; ++j) {
        const int r = tr + j * 16;
        float4 v = *(const float4*)(src + (size_t)(r0 + r) * C + c0 + tq);
        tile[tq + 0][r] = (bf16)v.x;
        tile[tq + 1][r] = (bf16)v.y;
        tile[tq + 2][r] = (bf16)v.z;
        tile[tq + 3][r] = (bf16)v.w;
    }
    __syncthreads();
    const int x8 = (threadIdx.x & 7) * 8;    // 8 bf16 = 16B per store
    const int cr = threadIdx.x >> 3;         // 32 rows per pass
#pragma unroll
    for (int j = 0; j < 2; ++j) {
        const int c = cr + j * 32;
        *(bf16x8*)(dst + (size_t)(c0 + c) * R + r0 + x8) = *(const bf16x8*)&tile[c][x8];
    }
}

// ------ grouped GEMM, 256x256 block, 8 waves of 128x64, BK=64, depth-2 ----------
// C[slot, n] = A[slot, kbase:kbase+KD] * B_e[n, kbase:kbase+KD]^T
// FIRST:  A = xb (via slot_tok), B = w1t, Out = Hg (bias+relu), SK=1
// !FIRST: A = Hg,                B = w2t, Out = Yg bf16 partials, SK=2
// LDS: 2 buffers x (256x64 A + 256x64 B) bf16 = 128KB -> 1 block/CU.
// Slot swizzle: LDS phys slot p at row r holds global 16B-slot p^(r&7); staging
// pre-swizzles the GLOBAL source (rule #21), reads XOR the slot with lr&7 ->
// quarter-wave frag reads spread across all 8 slot groups.
// 8 gloads/thread/tile; steady-state wait vmcnt(8) = next tile's loads in flight.
template<int KD, int ND, bool FIRST, int SK>
__global__ __launch_bounds__(512, 1)
void moe_gemm(const bf16* __restrict__ Adata, const bf16* __restrict__ Bt,
              const float* __restrict__ bias, bf16* __restrict__ Out,
              const int* __restrict__ slot_tok, const int* __restrict__ offsets,
              const int* __restrict__ tmap_e, const int* __restrict__ tmap_rt,
              const int* __restrict__ ntiles)
{
    constexpr int NX  = ND / 256;          // N-tiles: 8 (GEMM1) or 2 (GEMM2)
    constexpr int XD  = NX * SK;           // grid.x: 8 or 4
    constexpr int NWG = XD * MAXT256;      // 576 / 288 — both % 8 == 0
    constexpr int Q   = NWG / 8;
    constexpr int NT  = KD / 64;           // K-tiles: 8 (GEMM1) or 16 (GEMM2)

    const int orig = blockIdx.y * XD + blockIdx.x;       // HW dispatch order
    const int work = (orig & 7) * Q + (orig >> 3);       // bijective XCD chunking
    const int wy   = work / XD;                          // row-tile
    const int rem  = work - wy * XD;
    const int wx   = rem % NX;                           // N-tile (fastest: shares A)
    const int ks   = rem / NX;                           // K-slice
    if (wy >= *ntiles) return;

    const int e    = tmap_e[wy];
    const int rt   = tmap_rt[wy];
    const int row0 = offsets[e] + rt * 256;
    const int rowEnd = offsets[e + 1];
    const int nb   = wx * 256;
    const int kbase = ks * KD;

    __shared__ __align__(16) bf16 As[2 * 256 * 64];   // 64KB
    __shared__ __align__(16) bf16 Bs[2 * 256 * 64];   // 64KB

    const int t = threadIdx.x;
    const int w = t >> 6, l = t & 63;      // 8 waves
    const int wm = w >> 2, wn = w & 3;     // 2x4 wave grid, 128x64 per wave
    const int lr = l & 15;
    const int sl = l >> 4;                 // k slot quarter 0..3

    // staging: load j covers rows j*64 + (t>>3); physical slot (t&7) holds
    // global slot (t&7) ^ (row&7)  (row&7 == (t>>3)&7 since j*64 % 8 == 0)
    const int srow_sub = t >> 3;                               // 0..63
    const int scol = (((t & 7) ^ (srow_sub & 7)) * 8);         // swizzled k-elem

    const bf16* aSrcJ[4];
    const bf16* bSrcJ[4];
#pragma unroll
    for (int j = 0; j < 4; ++j) {
        const int r = j * 64 + srow_sub;
        int sr = row0 + r; if (sr >= NSLOT) sr = NSLOT - 1;
        if (FIRST) aSrcJ[j] = Adata + (size_t)slot_tok[sr] * (KD * SK) + kbase + scol;
        else       aSrcJ[j] = Adata + (size_t)sr * (KD * SK) + kbase + scol;
        bSrcJ[j] = Bt + ((size_t)e * ND + nb + r) * (KD * SK) + kbase + scol;
    }

    f32x4 acc[8][4] = {};

    auto STAGE = [&](int buf, int k0) {
#pragma unroll
        for (int j = 0; j < 4; ++j) {
            gload16(aSrcJ[j] + k0, As + buf * 16384 + j * 4096 + w * 512);
            gload16(bSrcJ[j] + k0, Bs + buf * 16384 + j * 4096 + w * 512);
        }
    };
    auto COMPUTE = [&](int buf) {
        const bf16* ab = As + buf * 16384;
        const bf16* bb = Bs + buf * 16384;
#pragma unroll
        for (int kk = 0; kk < 2; ++kk) {
            const int phys = ((kk * 4 + sl) ^ (lr & 7)) * 8;
            bf16x8 aF[8], bF[4];
#pragma unroll
            for (int mi = 0; mi < 8; ++mi)
                aF[mi] = *(const bf16x8*)(ab + (wm * 128 + mi * 16 + lr) * 64 + phys);
#pragma unroll
            for (int nj = 0; nj < 4; ++nj)
                bF[nj] = *(const bf16x8*)(bb + (wn * 64 + nj * 16 + lr) * 64 + phys);
#pragma unroll
            for (int mi = 0; mi < 8; ++mi)
#pragma unroll
                for (int nj = 0; nj < 4; ++nj)
                    acc[mi][nj] = __builtin_amdgcn_mfma_f32_16x16x32_bf16(
                        aF[mi], bF[nj], acc[mi][nj], 0, 0, 0);
        }
    };

    // prologue: 2 tiles in flight (16 loads/thread)
    STAGE(0, 0);
    STAGE(1, 64);
    __builtin_amdgcn_sched_barrier(0);

    for (int t2 = 0; t2 < NT - 2; ++t2) {
        // wait tile t2's 8 loads (next tile's 8 stay in flight)
        asm volatile("s_waitcnt vmcnt(8)" ::: "memory");
        __builtin_amdgcn_sched_barrier(0);
        __builtin_amdgcn_s_barrier();
        __builtin_amdgcn_sched_barrier(0);
        COMPUTE(t2 & 1);
        __builtin_amdgcn_s_barrier();            // all waves done reading buf
        __builtin_amdgcn_sched_barrier(0);
        STAGE(t2 & 1, (t2 + 2) * 64);
        __builtin_amdgcn_sched_barrier(0);
    }
    // tail: two tiles remain; vmcnt 8 -> 0
    asm volatile("s_waitcnt vmcnt(8)" ::: "memory");
    __builtin_amdgcn_sched_barrier(0);
    __builtin_amdgcn_s_barrier();
    __builtin_amdgcn_sched_barrier(0);
    COMPUTE(NT & 1);           // (NT-2) & 1
    asm volatile("s_waitcnt vmcnt(0)" ::: "memory");
    __builtin_amdgcn_sched_barrier(0);
    __builtin_amdgcn_s_barrier();
    __builtin_amdgcn_sched_barrier(0);
    COMPUTE((NT - 1) & 1);

    const int rowW = row0 + wm * 128;
    const int colW = nb + wn * 64;
    bf16* outBase = Out + (size_t)ks * NSLOT * ND;
#pragma unroll
    for (int mi = 0; mi < 8; ++mi) {
#pragma unroll
        for (int nj = 0; nj < 4; ++nj) {
#pragma unroll
            for (int r = 0; r < 4; ++r) {
                int row = rowW + mi * 16 + sl * 4 + r;
                int col = colW + nj * 16 + lr;
                if (row < rowEnd) {
                    float v = acc[mi][nj][r];
                    if (FIRST)        v = fmaxf(v + bias[e * ND + col], 0.f);
                    else if (ks == 0) v = v + bias[e * ND + col];
                    outBase[(size_t)row * ND + col] = (bf16)v;
                }
            }
        }
    }
}

// ---------------- combine: out[n] = w0*(Y0+Y1)[slot0] + w1*(Y0+Y1)[slot1] --------
__global__ __launch_bounds__(256)
void combine_kernel(const bf16* __restrict__ Yg, const int* __restrict__ pos,
                    const float* __restrict__ slot_w, float* __restrict__ out)
{
    const int idx = blockIdx.x * 256 + threadIdx.x;  // over NTOK*DDIM/8
    const int n  = idx >> 6;                          // DDIM/8 = 64
    const int d8 = (idx & 63) * 8;
    const int s0 = pos[n * 2 + 0], s1 = pos[n * 2 + 1];
    const float w0 = slot_w[s0], w1 = slot_w[s1];
    const bf16* y1 = Yg + (size_t)NSLOT * DDIM;
    bf16x8 a0 = *(const bf16x8*)(Yg + (size_t)s0 * DDIM + d8);
    bf16x8 a1 = *(const bf16x8*)(y1 + (size_t)s0 * DDIM + d8);
    bf16x8 b0 = *(const bf16x8*)(Yg + (size_t)s1 * DDIM + d8);
    bf16x8 b1 = *(const bf16x8*)(y1 + (size_t)s1 * DDIM + d8);
    float o[8];
#pragma unroll
    for (int j = 0; j < 8; ++j)
        o[j] = w0 * ((float)a0[j] + (float)a1[j]) + w1 * ((float)b0[j] + (float)b1[j]);
    float* op = out + (size_t)n * DDIM + d8;
    *(float4*)(op + 0) = make_float4(o[0], o[1], o[2], o[3]);
    *(float4*)(op + 4) = make_float4(o[4], o[5], o[6], o[7]);
}

extern "C" void kernel_launch(void* const* d_in, const int* in_sizes, int n_in,
                              void* d_out, int out_size, void* d_ws, size_t ws_size,
                              hipStream_t stream)
{
    (void)in_sizes; (void)n_in;
    const float* x  = (const float*)d_in[0];
    const float* Wg = (const float*)d_in[1];
    const float* bg = (const float*)d_in[2];
    const float* W1 = (const float*)d_in[3];
    const float* b1 = (const float*)d_in[4];
    const float* W2 = (const float*)d_in[5];
    const float* b2 = (const float*)d_in[6];
    float* out = (float*)d_out;

    uint8_t* ws = (uint8_t*)d_ws;
    size_t off = 0;
    auto alloc = [&](size_t bytes) -> void* {
        void* p = ws + off;
        off = (off + bytes + 255) & ~(size_t)255;
        return p;
    };
    bf16*  xb      = (bf16*)alloc((size_t)NTOK * DDIM * 2);
    bf16*  w1t     = (bf16*)alloc((size_t)NEXP * FDIM * DDIM * 2);  // [E][FF][D]
    bf16*  w2t     = (bf16*)alloc((size_t)NEXP * DDIM * FDIM * 2);  // [E][D][FF]
    bf16*  Hg      = (bf16*)alloc((size_t)NSLOT * FDIM * 2);
    bf16*  Yg      = (bf16*)alloc((size_t)2 * NSLOT * DDIM * 2);    // 2 K-slices
    int*   counts  = (int*)alloc(NEXP * 4);
    int*   cursors = (int*)alloc(NEXP * 4);
    int*   offsets = (int*)alloc((NEXP + 1) * 4);
    int*   ntiles  = (int*)alloc(4);
    int*   tmap_e  = (int*)alloc(MAXT256 * 4);
    int*   tmap_rt = (int*)alloc(MAXT256 * 4);
    int*   top_idx = (int*)alloc((size_t)NTOK * 2 * 4);
    float* top_w   = (float*)alloc((size_t)NTOK * 2 * 4);
    int*   pos     = (int*)alloc((size_t)NTOK * 2 * 4);
    int*   slot_tok= (int*)alloc((size_t)NSLOT * 4);
    float* slot_w  = (float*)alloc((size_t)NSLOT * 4);

    if (ws_size < off) {
        // workspace too small: distinguishable failure signature (out = 0)
        hipMemsetAsync(d_out, 0, (size_t)out_size * 4, stream);
        return;
    }

    hipMemsetAsync(counts, 0, NEXP * 4, stream);

    gating_kernel<<<1024, 256, 0, stream>>>(x, Wg, bg, xb, top_idx, top_w, counts);
    scan_kernel<<<1, 64, 0, stream>>>(counts, offsets, tmap_e, tmap_rt, ntiles, cursors);
    scatter_kernel<<<NTOK / 256, 256, 0, stream>>>(top_idx, top_w, offsets, cursors,
                                                   slot_tok, slot_w, pos);
    transpose_cvt<<<dim3(FDIM / 64, DDIM / 64, NEXP), 256, 0, stream>>>(W1, w1t, DDIM, FDIM);
    transpose_cvt<<<dim3(DDIM / 64, FDIM / 64, NEXP), 256, 0, stream>>>(W2, w2t, FDIM, DDIM);

    moe_gemm<DDIM, FDIM, true, 1><<<dim3(FDIM / 256, MAXT256), 512, 0, stream>>>(
        xb, w1t, b1, Hg, slot_tok, offsets, tmap_e, tmap_rt, ntiles);
    moe_gemm<FDIM / 2, DDIM, false, 2><<<dim3((DDIM / 256) * 2, MAXT256), 512, 0, stream>>>(
        Hg, w2t, b2, Yg, slot_tok, offsets, tmap_e, tmap_rt, ntiles);

    combine_kernel<<<(NTOK * DDIM / 8) / 256, 256, 0, stream>>>(Yg, pos, slot_w, out);
}

// Round 9
// 178.968 us; speedup vs baseline: 1.3439x; 1.3439x over previous
//
#include <hip/hip_runtime.h>
#include <hip/hip_bf16.h>
#include <cstdint>

// Problem constants (from reference): B=4, T=2048, D=512, FF=2048, E=8, K=2
#define NTOK   8192      // B*T
#define DDIM   512
#define FDIM   2048
#define NEXP   8
#define NSLOT  16384     // 2*NTOK assignments (top-2, always exactly 2 per token)
#define MAXTILES 136     // sum_e ceil(cnt_e/128) <= 16384/128 + 8

typedef __bf16 bf16;
typedef __bf16 bf16x8 __attribute__((ext_vector_type(8)));
typedef float  f32x4  __attribute__((ext_vector_type(4)));

typedef uint32_t __attribute__((address_space(1))) gu32;
typedef uint32_t __attribute__((address_space(3))) lu32;

// async global->LDS, 16B per lane; LDS dest must be wave-uniform base (+lane*16 implicit)
__device__ __forceinline__ void gload16(const void* g, void* l) {
    __builtin_amdgcn_global_load_lds((const gu32*)(uintptr_t)g,
                                     (lu32*)(uintptr_t)l, 16, 0, 0);
}

// ---------------- gating: logits -> softmax -> top2 -> weights; also x->bf16 ----
__global__ __launch_bounds__(256)
void gating_kernel(const float* __restrict__ x, const float* __restrict__ Wg,
                   const float* __restrict__ bg, bf16* __restrict__ xb,
                   int* __restrict__ top_idx, float* __restrict__ top_w,
                   int* __restrict__ counts)
{
    __shared__ int cnt_s[NEXP];
    if (threadIdx.x < NEXP) cnt_s[threadIdx.x] = 0;
    __syncthreads();

    const int w = threadIdx.x >> 6;
    const int l = threadIdx.x & 63;
    const int gw = blockIdx.x * 4 + w;   // 1024 blocks * 4 waves = 4096 waves

    for (int n = gw; n < NTOK; n += 4096) {
        const float4* xp = (const float4*)(x + (size_t)n * DDIM + l * 8);
        float4 x0 = xp[0], x1 = xp[1];
        float xf[8] = {x0.x, x0.y, x0.z, x0.w, x1.x, x1.y, x1.z, x1.w};

        bf16x8 xv;
#pragma unroll
        for (int i = 0; i < 8; ++i) xv[i] = (bf16)xf[i];
        *(bf16x8*)(xb + (size_t)n * DDIM + l * 8) = xv;

        float acc[8] = {0.f,0.f,0.f,0.f,0.f,0.f,0.f,0.f};
#pragma unroll
        for (int i = 0; i < 8; ++i) {
            const float4* wp = (const float4*)(Wg + (size_t)(l * 8 + i) * NEXP);
            float4 wa = wp[0], wb = wp[1];
            acc[0] += xf[i] * wa.x; acc[1] += xf[i] * wa.y;
            acc[2] += xf[i] * wa.z; acc[3] += xf[i] * wa.w;
            acc[4] += xf[i] * wb.x; acc[5] += xf[i] * wb.y;
            acc[6] += xf[i] * wb.z; acc[7] += xf[i] * wb.w;
        }
#pragma unroll
        for (int m = 32; m >= 1; m >>= 1)
#pragma unroll
            for (int e = 0; e < 8; ++e)
                acc[e] += __shfl_xor(acc[e], m);

        if (l == 0) {
            float logit[8];
#pragma unroll
            for (int e = 0; e < 8; ++e) logit[e] = acc[e] + bg[e];
            float mx = logit[0];
#pragma unroll
            for (int e = 1; e < 8; ++e) mx = fmaxf(mx, logit[e]);
            float g[8], s = 0.f;
#pragma unroll
            for (int e = 0; e < 8; ++e) { g[e] = expf(logit[e] - mx); s += g[e]; }
            float inv = 1.f / s;
#pragma unroll
            for (int e = 0; e < 8; ++e) g[e] *= inv;
            // top-2, ties -> lower index first (matches lax.top_k)
            int e0 = 0;
#pragma unroll
            for (int e = 1; e < 8; ++e) if (g[e] > g[e0]) e0 = e;
            int e1 = (e0 == 0) ? 1 : 0;
#pragma unroll
            for (int e = 0; e < 8; ++e) if (e != e0 && e != e1 && g[e] > g[e1]) e1 = e;
            float denom = g[e0] + g[e1] + 0.01f;
            top_idx[n * 2 + 0] = e0;
            top_idx[n * 2 + 1] = e1;
            top_w[n * 2 + 0] = g[e0] / denom;
            top_w[n * 2 + 1] = g[e1] / denom;
            atomicAdd(&cnt_s[e0], 1);
            atomicAdd(&cnt_s[e1], 1);
        }
    }
    __syncthreads();
    if (threadIdx.x < NEXP) atomicAdd(&counts[threadIdx.x], cnt_s[threadIdx.x]);
}

// ---------------- scan: offsets, tile map, zero cursors (single thread, tiny) ----
__global__ void scan_kernel(const int* __restrict__ counts, int* __restrict__ offsets,
                            int* __restrict__ tmap_e, int* __restrict__ tmap_rt,
                            int* __restrict__ ntiles, int* __restrict__ cursors)
{
    if (threadIdx.x == 0) {
        int off = 0;
        for (int e = 0; e < NEXP; ++e) { offsets[e] = off; off += counts[e]; cursors[e] = 0; }
        offsets[NEXP] = off;
        int t = 0;
        for (int e = 0; e < NEXP; ++e) {
            int nt = (counts[e] + 127) >> 7;
            for (int rt = 0; rt < nt; ++rt) { tmap_e[t] = e; tmap_rt[t] = rt; ++t; }
        }
        *ntiles = t;
    }
}

// ---------------- scatter: block-aggregated cursor reservation ------------------
__global__ __launch_bounds__(256)
void scatter_kernel(const int* __restrict__ top_idx, const float* __restrict__ top_w,
                    const int* __restrict__ offsets, int* __restrict__ cursors,
                    int* __restrict__ slot_tok, float* __restrict__ slot_w,
                    int* __restrict__ pos)
{
    __shared__ int lcnt[NEXP];
    __shared__ int lbase[NEXP];
    const int t = threadIdx.x;
    if (t < NEXP) lcnt[t] = 0;
    __syncthreads();
    const int n = blockIdx.x * 256 + t;   // NTOK = 32*256 exactly
    const int e0 = top_idx[n * 2 + 0];
    const int e1 = top_idx[n * 2 + 1];
    const int r0 = atomicAdd(&lcnt[e0], 1);
    const int r1 = atomicAdd(&lcnt[e1], 1);
    __syncthreads();
    if (t < NEXP) lbase[t] = atomicAdd(&cursors[t], lcnt[t]);
    __syncthreads();
    const int s0 = offsets[e0] + lbase[e0] + r0;
    const int s1 = offsets[e1] + lbase[e1] + r1;
    slot_tok[s0] = n; slot_w[s0] = top_w[n * 2 + 0]; pos[n * 2 + 0] = s0;
    slot_tok[s1] = n; slot_w[s1] = top_w[n * 2 + 1]; pos[n * 2 + 1] = s1;
}

// ---------------- fp32 [E][R][C] -> bf16 [E][C][R] transpose+convert ------------
__global__ __launch_bounds__(256)
void transpose_cvt(const float* __restrict__ src, bf16* __restrict__ dst, int R, int C)
{
    __shared__ bf16 tile[64][72];   // 72 = 16B-aligned row stride, rotates banks
    const size_t eo = (size_t)blockIdx.z * R * C;
    src += eo; dst += eo;
    const int c0 = blockIdx.x * 64, r0 = blockIdx.y * 64;
    const int tq = (threadIdx.x & 15) * 4;   // col quad within 64
    const int tr = threadIdx.x >> 4;         // 16 rows per pass
#pragma unroll
    for (int j = 0; j < 4; ++j) {
        const int r = tr + j * 16;
        float4 v = *(const float4*)(src + (size_t)(r0 + r) * C + c0 + tq);
        tile[tq + 0][r] = (bf16)v.x;
        tile[tq + 1][r] = (bf16)v.y;
        tile[tq + 2][r] = (bf16)v.z;
        tile[tq + 3][r] = (bf16)v.w;
    }
    __syncthreads();
    const int x8 = (threadIdx.x & 7) * 8;    // 8 bf16 = 16B per store
    const int cr = threadIdx.x >> 3;         // 32 rows per pass
#pragma unroll
    for (int j = 0; j < 2; ++j) {
        const int c = cr + j * 32;
        *(bf16x8*)(dst + (size_t)(c0 + c) * R + r0 + x8) = *(const bf16x8*)&tile[c][x8];
    }
}

// ---------------- grouped GEMM, 8-wave 128x128, depth-2 vmcnt + XCD swizzle -----
// (R5 geometry — best measured — with depth 3->2: 32KB LDS -> 5 blocks/CU.)
// C[slot, n] = A[slot, :KD] * B_e[n, :KD]^T
// FIRST:  A = xb (via slot_tok indirection), B = w1t, Out = Hg (bias+relu+bf16)
// !FIRST: A = Hg (direct slot rows),         B = w2t, Out = Yg (bias, bf16)
// 512 threads = 8 waves (wave grid 4x2, each wave 32x64 output).
// LDS: 2 tile-buffers x (4KB A + 4KB B)... per buffer 128x32x2B x2 = 16KB -> 32KB.
// 2 gloads/wave/tile; steady-state wait vmcnt(2) = next tile's loads in flight.
template<int KD, int ND, bool FIRST>
__global__ __launch_bounds__(512)
void moe_gemm(const bf16* __restrict__ Adata, const bf16* __restrict__ Bt,
              const float* __restrict__ bias, bf16* __restrict__ Out,
              const int* __restrict__ slot_tok, const int* __restrict__ offsets,
              const int* __restrict__ tmap_e, const int* __restrict__ tmap_rt,
              const int* __restrict__ ntiles)
{
    constexpr int NX  = ND / 128;          // N-tiles: 16 (GEMM1) or 4 (GEMM2)
    constexpr int NWG = NX * MAXTILES;     // 2176 / 544 — both % 8 == 0
    constexpr int Q   = NWG / 8;
    constexpr int NT  = KD / 32;           // K-tiles: 16 (GEMM1) or 64 (GEMM2)

    const int orig = blockIdx.y * NX + blockIdx.x;       // HW dispatch order
    const int work = (orig & 7) * Q + (orig >> 3);       // bijective XCD chunking
    const int wy   = work / NX;                          // row-tile
    const int wx   = work - wy * NX;                     // N-tile (fastest: shares A)
    if (wy >= *ntiles) return;

    const int e    = tmap_e[wy];
    const int rt   = tmap_rt[wy];
    const int row0 = offsets[e] + rt * 128;
    const int rowEnd = offsets[e + 1];
    const int nb   = wx * 128;

    // double-buffered LDS: [2] x 128x32 bf16 for A and B  (32KB total)
    __shared__ __align__(16) bf16 As[2 * 128 * 32];
    __shared__ __align__(16) bf16 Bs[2 * 128 * 32];

    const int t = threadIdx.x;
    const int w = t >> 6, l = t & 63;      // 8 waves
    const int wm = w >> 1, wn = w & 1;     // 4x2 wave grid, 32x64 per wave

    // staging: wave w stages rows w*16 .. w*16+15 of A-tile and B-tile (1KB each)
    const int rA   = w * 16 + (l >> 2);
    const int colb = (l & 3) * 8;

    int srow = row0 + rA; if (srow >= NSLOT) srow = NSLOT - 1;
    const bf16* aSrc;
    if (FIRST) aSrc = Adata + (size_t)slot_tok[srow] * KD + colb;
    else       aSrc = Adata + (size_t)srow * KD + colb;
    const bf16* bSrc = Bt + ((size_t)e * ND + nb + rA) * KD + colb;

    const int offW = w * 512;   // elem offset of this wave's 1KB chunk

    f32x4 acc[2][4] = {};
    const int lr = l & 15;
    const int lk = (l >> 4) * 8;

    auto STAGE = [&](int buf, int k0) {
        gload16(aSrc + k0, As + buf * 4096 + offW);
        gload16(bSrc + k0, Bs + buf * 4096 + offW);
    };
    auto COMPUTE = [&](int buf) {
        const bf16* ab = As + buf * 4096;
        const bf16* bb = Bs + buf * 4096;
        bf16x8 aF[2], bF[4];
#pragma unroll
        for (int mi = 0; mi < 2; ++mi)
            aF[mi] = *(const bf16x8*)(ab + (wm * 32 + mi * 16 + lr) * 32 + lk);
#pragma unroll
        for (int nj = 0; nj < 4; ++nj)
            bF[nj] = *(const bf16x8*)(bb + (wn * 64 + nj * 16 + lr) * 32 + lk);
#pragma unroll
        for (int mi = 0; mi < 2; ++mi)
#pragma unroll
            for (int nj = 0; nj < 4; ++nj)
                acc[mi][nj] = __builtin_amdgcn_mfma_f32_16x16x32_bf16(
                    aF[mi], bF[nj], acc[mi][nj], 0, 0, 0);
    };

    // prologue: 2 tiles in flight (4 loads/wave)
    STAGE(0, 0);
    STAGE(1, 32);
    __builtin_amdgcn_sched_barrier(0);

    for (int t2 = 0; t2 < NT - 2; ++t2) {
        // wait for tile t2's 2 loads (next tile's 2 stay in flight)
        asm volatile("s_waitcnt vmcnt(2)" ::: "memory");
        __builtin_amdgcn_sched_barrier(0);
        __builtin_amdgcn_s_barrier();
        __builtin_amdgcn_sched_barrier(0);
        COMPUTE(t2 & 1);
        __builtin_amdgcn_s_barrier();            // all waves done reading buf
        __builtin_amdgcn_sched_barrier(0);
        STAGE(t2 & 1, (t2 + 2) * 32);
        __builtin_amdgcn_sched_barrier(0);
    }
    // tail: two tiles remain; vmcnt 2 -> 0
    asm volatile("s_waitcnt vmcnt(2)" ::: "memory");
    __builtin_amdgcn_sched_barrier(0);
    __builtin_amdgcn_s_barrier();
    __builtin_amdgcn_sched_barrier(0);
    COMPUTE(NT & 1);            // (NT-2) & 1
    __builtin_amdgcn_s_barrier();
    __builtin_amdgcn_sched_barrier(0);
    asm volatile("s_waitcnt vmcnt(0)" ::: "memory");
    __builtin_amdgcn_sched_barrier(0);
    __builtin_amdgcn_s_barrier();
    __builtin_amdgcn_sched_barrier(0);
    COMPUTE((NT - 1) & 1);

    const int rowW = row0 + wm * 32;
    const int colW = nb + wn * 64;
#pragma unroll
    for (int mi = 0; mi < 2; ++mi) {
#pragma unroll
        for (int nj = 0; nj < 4; ++nj) {
#pragma unroll
            for (int r = 0; r < 4; ++r) {
                int row = rowW + mi * 16 + (l >> 4) * 4 + r;
                int col = colW + nj * 16 + lr;
                if (row < rowEnd) {
                    float v = acc[mi][nj][r] + bias[e * ND + col];
                    if (FIRST) v = fmaxf(v, 0.f);
                    Out[(size_t)row * ND + col] = (bf16)v;
                }
            }
        }
    }
}

// ---------------- combine: out[n] = w0*Y[slot0] + w1*Y[slot1] (bf16 Y) ----------
__global__ __launch_bounds__(256)
void combine_kernel(const bf16* __restrict__ Yg, const int* __restrict__ pos,
                    const float* __restrict__ slot_w, float* __restrict__ out)
{
    const int idx = blockIdx.x * 256 + threadIdx.x;  // over NTOK*DDIM/8
    const int n  = idx >> 6;                          // DDIM/8 = 64
    const int d8 = (idx & 63) * 8;
    const int s0 = pos[n * 2 + 0], s1 = pos[n * 2 + 1];
    const float w0 = slot_w[s0], w1 = slot_w[s1];
    bf16x8 a = *(const bf16x8*)(Yg + (size_t)s0 * DDIM + d8);
    bf16x8 b = *(const bf16x8*)(Yg + (size_t)s1 * DDIM + d8);
    float o[8];
#pragma unroll
    for (int j = 0; j < 8; ++j)
        o[j] = w0 * (float)a[j] + w1 * (float)b[j];
    float* op = out + (size_t)n * DDIM + d8;
    *(float4*)(op + 0) = make_float4(o[0], o[1], o[2], o[3]);
    *(float4*)(op + 4) = make_float4(o[4], o[5], o[6], o[7]);
}

extern "C" void kernel_launch(void* const* d_in, const int* in_sizes, int n_in,
                              void* d_out, int out_size, void* d_ws, size_t ws_size,
                              hipStream_t stream)
{
    (void)in_sizes; (void)n_in;
    const float* x  = (const float*)d_in[0];
    const float* Wg = (const float*)d_in[1];
    const float* bg = (const float*)d_in[2];
    const float* W1 = (const float*)d_in[3];
    const float* b1 = (const float*)d_in[4];
    const float* W2 = (const float*)d_in[5];
    const float* b2 = (const float*)d_in[6];
    float* out = (float*)d_out;

    uint8_t* ws = (uint8_t*)d_ws;
    size_t off = 0;
    auto alloc = [&](size_t bytes) -> void* {
        void* p = ws + off;
        off = (off + bytes + 255) & ~(size_t)255;
        return p;
    };
    bf16*  xb      = (bf16*)alloc((size_t)NTOK * DDIM * 2);
    bf16*  w1t     = (bf16*)alloc((size_t)NEXP * FDIM * DDIM * 2);  // [E][FF][D]
    bf16*  w2t     = (bf16*)alloc((size_t)NEXP * DDIM * FDIM * 2);  // [E][D][FF]
    bf16*  Hg      = (bf16*)alloc((size_t)NSLOT * FDIM * 2);
    bf16*  Yg      = (bf16*)alloc((size_t)NSLOT * DDIM * 2);
    int*   counts  = (int*)alloc(NEXP * 4);
    int*   cursors = (int*)alloc(NEXP * 4);
    int*   offsets = (int*)alloc((NEXP + 1) * 4);
    int*   ntiles  = (int*)alloc(4);
    int*   tmap_e  = (int*)alloc(MAXTILES * 4);
    int*   tmap_rt = (int*)alloc(MAXTILES * 4);
    int*   top_idx = (int*)alloc((size_t)NTOK * 2 * 4);
    float* top_w   = (float*)alloc((size_t)NTOK * 2 * 4);
    int*   pos     = (int*)alloc((size_t)NTOK * 2 * 4);
    int*   slot_tok= (int*)alloc((size_t)NSLOT * 4);
    float* slot_w  = (float*)alloc((size_t)NSLOT * 4);

    if (ws_size < off) {
        // workspace too small: distinguishable failure signature (out = 0)
        hipMemsetAsync(d_out, 0, (size_t)out_size * 4, stream);
        return;
    }

    hipMemsetAsync(counts, 0, NEXP * 4, stream);

    gating_kernel<<<1024, 256, 0, stream>>>(x, Wg, bg, xb, top_idx, top_w, counts);
    scan_kernel<<<1, 64, 0, stream>>>(counts, offsets, tmap_e, tmap_rt, ntiles, cursors);
    scatter_kernel<<<NTOK / 256, 256, 0, stream>>>(top_idx, top_w, offsets, cursors,
                                                   slot_tok, slot_w, pos);
    transpose_cvt<<<dim3(FDIM / 64, DDIM / 64, NEXP), 256, 0, stream>>>(W1, w1t, DDIM, FDIM);
    transpose_cvt<<<dim3(DDIM / 64, FDIM / 64, NEXP), 256, 0, stream>>>(W2, w2t, FDIM, DDIM);

    moe_gemm<DDIM, FDIM, true><<<dim3(FDIM / 128, MAXTILES), 512, 0, stream>>>(
        xb, w1t, b1, Hg, slot_tok, offsets, tmap_e, tmap_rt, ntiles);
    moe_gemm<FDIM, DDIM, false><<<dim3(DDIM / 128, MAXTILES), 512, 0, stream>>>(
        Hg, w2t, b2, Yg, slot_tok, offsets, tmap_e, tmap_rt, ntiles);

    combine_kernel<<<(NTOK * DDIM / 8) / 256, 256, 0, stream>>>(Yg, pos, slot_w, out);
}